// Round 5
// baseline (492.342 us; speedup 1.0000x reference)
//
#include <hip/hip_runtime.h>
#include <hip/hip_bf16.h>
#include <math.h>

#define BB 2
#define NPIX 131072            // 2*256*256

// ws float header
#define WS_G    0              // [B][64][16] = 2048  (G[c=h*16+d][e])
#define WS_SSQ  2048           // [2][B][64]  = 256 (0=q,1=k)
#define WS_M    2304           // [B][c][o]   = 8192 (folded Wp*blockdiag(attn), transposed)
#define WS_HDR  10496
#define WS_M2_BYTE ((size_t)WS_HDR*4)   // m2 bf16: NPIX*64*2 = 16.78 MB

// ---------------------------------------------------------------------------
// K1: q,k,v projections from x. v -> d_out. G + ssq atomics -> ws header.
// Weights in blocked-f4 LDS layout: wt[mat*4096 + c4*256 + o*4 + u], so each
// lane reads its 4 weights as one conflict-free ds_read_b128.
// LDS = 48 + 8 + 2 = 58 KB -> 2 blocks/CU.
// ---------------------------------------------------------------------------
__global__ __launch_bounds__(256, 2) void k_qkv3(const float* __restrict__ x,
    const float* __restrict__ Wq, const float* __restrict__ Wk,
    const float* __restrict__ Wv, float* __restrict__ ws,
    float* __restrict__ vout)
{
    __shared__ float wt[3*4096];        // 48 KB
    __shared__ float buf[4][8][64];     // 8 KB per-wave activation buffer
    __shared__ float s_ssq[4][2][64];   // 2 KB
    const int tid = threadIdx.x, lane = tid & 63, w = tid >> 6;
    const int blk = blockIdx.x, b = blk >> 8;

    // stage weights: LDS index i -> (c4=i>>8, o=(i>>2)&63, u=i&3); global [o][c]
    for (int i = tid; i < 4096; i += 256) {
        const int o = (i >> 2) & 63, gc = (i >> 8) * 4 + (i & 3);
        wt[i]        = Wq[o*64 + gc];
        wt[4096 + i] = Wk[o*64 + gc];
        wt[8192 + i] = Wv[o*64 + gc];
    }
    __syncthreads();

    float accG[16];
#pragma unroll
    for (int e = 0; e < 16; ++e) accG[e] = 0.f;
    float ssq_q = 0.f, ssq_k = 0.f;
    const int hbase = lane & 48;
    const int pix0 = blk*256 + w*64;

    for (int g = 0; g < 8; ++g) {
        const int pbase = pix0 + g*8;
#pragma unroll
        for (int j = 0; j < 8; ++j)
            buf[w][j][lane] = x[(size_t)(pbase+j)*64 + lane];
        __builtin_amdgcn_wave_barrier();

        float accQ[8], accK[8], accV[8];
#pragma unroll
        for (int j = 0; j < 8; ++j) { accQ[j]=0.f; accK[j]=0.f; accV[j]=0.f; }
        for (int c4 = 0; c4 < 16; ++c4) {
            float4 x4[8];
#pragma unroll
            for (int j = 0; j < 8; ++j)
                x4[j] = *(const float4*)&buf[w][j][c4*4];       // broadcast
            const float4 wq4 = *(const float4*)&wt[c4*256 + lane*4];
            const float4 wk4 = *(const float4*)&wt[4096 + c4*256 + lane*4];
            const float4 wv4 = *(const float4*)&wt[8192 + c4*256 + lane*4];
#pragma unroll
            for (int u = 0; u < 4; ++u) {
                const float wq = (&wq4.x)[u], wk = (&wk4.x)[u], wv = (&wv4.x)[u];
#pragma unroll
                for (int j = 0; j < 8; ++j) {
                    const float xc = (&x4[j].x)[u];
                    accQ[j] = fmaf(xc, wq, accQ[j]);
                    accK[j] = fmaf(xc, wk, accK[j]);
                    accV[j] = fmaf(xc, wv, accV[j]);
                }
            }
        }
        __builtin_amdgcn_wave_barrier();
#pragma unroll
        for (int j = 0; j < 8; ++j) {
            vout[(size_t)(pbase+j)*64 + lane] = accV[j];
            buf[w][j][lane] = accQ[j];                          // x dead
            ssq_q = fmaf(accQ[j], accQ[j], ssq_q);
            ssq_k = fmaf(accK[j], accK[j], ssq_k);
        }
        __builtin_amdgcn_wave_barrier();
        // Gram: lane c=h*16+d holds k; q[h*16+e] broadcast
#pragma unroll
        for (int j = 0; j < 8; ++j) {
            const float kv = accK[j];
#pragma unroll
            for (int e4 = 0; e4 < 4; ++e4) {
                float4 q4 = *(const float4*)&buf[w][j][hbase + e4*4];
                accG[e4*4+0] = fmaf(kv, q4.x, accG[e4*4+0]);
                accG[e4*4+1] = fmaf(kv, q4.y, accG[e4*4+1]);
                accG[e4*4+2] = fmaf(kv, q4.z, accG[e4*4+2]);
                accG[e4*4+3] = fmaf(kv, q4.w, accG[e4*4+3]);
            }
        }
        __builtin_amdgcn_wave_barrier();
    }

    // RACE FIX (round 4 bug): waves 0/1's phase-1 writes below span OTHER
    // waves' buf regions; must wait until ALL waves finished the main loop.
    __syncthreads();

    // two-phase block reduction of G in buf (2048 floats), layout [w2][e][lane]
    float* gr = &buf[0][0][0];
    if (w < 2) {
#pragma unroll
        for (int e = 0; e < 16; ++e) gr[w*1024 + e*64 + lane] = accG[e];
    }
    s_ssq[w][0][lane] = ssq_q;
    s_ssq[w][1][lane] = ssq_k;
    __syncthreads();
    if (w >= 2) {
#pragma unroll
        for (int e = 0; e < 16; ++e) gr[(w-2)*1024 + e*64 + lane] += accG[e];
    }
    __syncthreads();
    float* Gg = ws + WS_G + (size_t)b*1024;
    for (int idx = tid; idx < 1024; idx += 256) {
        const int e = idx >> 6, c = idx & 63;
        atomicAdd(&Gg[c*16 + e], gr[idx] + gr[1024 + idx]);
    }
    if (tid < 128) {
        const int which = tid >> 6, cidx = tid & 63;
        float s = s_ssq[0][which][cidx] + s_ssq[1][which][cidx]
                + s_ssq[2][which][cidx] + s_ssq[3][which][cidx];
        atomicAdd(ws + WS_SSQ + (size_t)which*(BB*64) + b*64 + cidx, s);
    }
}

// ---------------------------------------------------------------------------
// K2: m1 = mask@w1^T+b1 ; vm0 = v*m1 -> d_out (in place) ; m2 -> ws bf16.
// LDS = 32 + 8 = 40 KB -> 4 blocks/CU.
// ---------------------------------------------------------------------------
__global__ __launch_bounds__(256, 4) void k_mask2(const float* __restrict__ mask,
    const float* __restrict__ w1, const float* __restrict__ b1,
    const float* __restrict__ w2, const float* __restrict__ b2,
    float* __restrict__ vio, __hip_bfloat16* __restrict__ m2out)
{
    __shared__ float wt[2*4096];        // 32 KB blocked-f4
    __shared__ float buf[4][8][64];     // 8 KB
    const int tid = threadIdx.x, lane = tid & 63, w = tid >> 6;
    const int blk = blockIdx.x;

    for (int i = tid; i < 4096; i += 256) {
        const int o = (i >> 2) & 63, gc = (i >> 8) * 4 + (i & 3);
        wt[i]        = w1[o*64 + gc];
        wt[4096 + i] = w2[o*64 + gc];
    }
    __syncthreads();
    const float bb1 = b1[lane], bb2 = b2[lane];
    const int pix0 = blk*256 + w*64;

    for (int g = 0; g < 8; ++g) {
        const int pbase = pix0 + g*8;
        float vreg[8];
#pragma unroll
        for (int j = 0; j < 8; ++j) {
            buf[w][j][lane] = mask[(size_t)(pbase+j)*64 + lane];
            vreg[j] = vio[(size_t)(pbase+j)*64 + lane];
        }
        __builtin_amdgcn_wave_barrier();

        float acc1[8];
#pragma unroll
        for (int j = 0; j < 8; ++j) acc1[j] = bb1;
        for (int c4 = 0; c4 < 16; ++c4) {
            float4 x4[8];
#pragma unroll
            for (int j = 0; j < 8; ++j)
                x4[j] = *(const float4*)&buf[w][j][c4*4];
            const float4 w4 = *(const float4*)&wt[c4*256 + lane*4];
#pragma unroll
            for (int u = 0; u < 4; ++u) {
#pragma unroll
                for (int j = 0; j < 8; ++j)
                    acc1[j] = fmaf((&x4[j].x)[u], (&w4.x)[u], acc1[j]);
            }
        }
        __builtin_amdgcn_wave_barrier();
#pragma unroll
        for (int j = 0; j < 8; ++j) {
            vio[(size_t)(pbase+j)*64 + lane] = vreg[j] * acc1[j];   // vm0
            buf[w][j][lane] = acc1[j];                              // mask dead
        }
        __builtin_amdgcn_wave_barrier();

        float acc2[8];
#pragma unroll
        for (int j = 0; j < 8; ++j) acc2[j] = bb2;
        for (int c4 = 0; c4 < 16; ++c4) {
            float4 a4[8];
#pragma unroll
            for (int j = 0; j < 8; ++j)
                a4[j] = *(const float4*)&buf[w][j][c4*4];
            const float4 w4 = *(const float4*)&wt[4096 + c4*256 + lane*4];
#pragma unroll
            for (int u = 0; u < 4; ++u) {
#pragma unroll
                for (int j = 0; j < 8; ++j)
                    acc2[j] = fmaf((&a4[j].x)[u], (&w4.x)[u], acc2[j]);
            }
        }
#pragma unroll
        for (int j = 0; j < 8; ++j)
            m2out[(size_t)(pbase+j)*64 + lane] = __float2bfloat16(acc2[j]);
        __builtin_amdgcn_wave_barrier();
    }
}

// ---------------------------------------------------------------------------
// K3: softmax over normalized Gram, folded with Wp:
//   Mt[b][c=h*16+e][o] = sum_d Wp[o][h*16+d] * attn[b][h][d][e].  2 blocks.
// ---------------------------------------------------------------------------
__global__ __launch_bounds__(256) void k_attn(const float* __restrict__ rescale,
    const float* __restrict__ Wp, float* __restrict__ ws)
{
    __shared__ float sAtt[1024];        // [h][d][e]
    const int b = blockIdx.x, t = threadIdx.x;
    const int d = t >> 4, e = t & 15;
    const float* ssq = ws + WS_SSQ;
    const float* G = ws + WS_G + (size_t)b*1024;
#pragma unroll
    for (int h = 0; h < 4; ++h) {
        float nk = fmaxf(sqrtf(ssq[BB*64 + b*64 + h*16 + d]), 1e-12f);
        float nq = fmaxf(sqrtf(ssq[b*64 + h*16 + e]), 1e-12f);
        float val = G[(h*16+d)*16 + e] / (nk*nq) * rescale[h];
        float m = val;
        for (int off = 1; off < 16; off <<= 1) m = fmaxf(m, __shfl_xor(m, off, 16));
        float ev = expf(val - m);
        float s = ev;
        for (int off = 1; off < 16; off <<= 1) s += __shfl_xor(s, off, 16);
        sAtt[h*256 + d*16 + e] = ev / s;
    }
    __syncthreads();
    float* Mtb = ws + WS_M + (size_t)b*4096;
    for (int idx = t; idx < 4096; idx += 256) {
        const int c = idx >> 6, o = idx & 63, h = c >> 4, ee = c & 15;
        float acc = 0.f;
#pragma unroll
        for (int d2 = 0; d2 < 16; ++d2)
            acc = fmaf(Wp[o*64 + h*16 + d2], sAtt[h*256 + d2*16 + ee], acc);
        Mtb[c*64 + o] = acc;
    }
}

// ---------------------------------------------------------------------------
// K4: per 8x8 tile: dwconv5x5(m2 bf16 halo in LDS as ushort)+dwb -> sigmoid ->
//   vm = vm0(d_out)*(1+sig) -> out = Mt . vm + bp.
// LDS = 18.4 + 16 + 4 = 38.4 KB -> 3+ blocks/CU.
// ---------------------------------------------------------------------------
__global__ __launch_bounds__(256, 3) void k_final(
    const __hip_bfloat16* __restrict__ m2g, const float* __restrict__ wsM,
    const float* __restrict__ bp, const float* __restrict__ dw,
    const float* __restrict__ dwb, float* __restrict__ out)
{
    __shared__ unsigned short m2s[144*64];  // 18.4 KB bf16 halo (0 outside)
    __shared__ float Mtl[4096];             // 16 KB blocked-f4 [c4][o][u]
    __shared__ float s_vm[4][4][64];        // per-wave
    const int tid = threadIdx.x, lane = tid & 63, w = tid >> 6;
    const int bid = blockIdx.x;
    const int b = bid >> 10, tile = bid & 1023;
    const int y0 = (tile >> 5) * 8, x0 = (tile & 31) * 8;
    const int c = lane;

    const float* Msrc = wsM + (size_t)b*4096;
    for (int i = tid; i < 4096; i += 256) {
        const int o = (i >> 2) & 63, gc = (i >> 8) * 4 + (i & 3);
        Mtl[i] = Msrc[gc*64 + o];
    }
    for (int i2 = tid; i2 < 2304; i2 += 256) {
        const int pos = i2 >> 4, c4 = (i2 & 15) * 4;
        const int yy = pos / 12, xx = pos - yy*12;
        const int gy = y0 + yy - 2, gx = x0 + xx - 2;
        ushort4 us = make_ushort4(0, 0, 0, 0);
        if (gy >= 0 && gy < 256 && gx >= 0 && gx < 256)
            us = *(const ushort4*)&m2g[(((size_t)b*256 + gy)*256 + gx)*64 + c4];
        *(ushort4*)&m2s[pos*64 + c4] = us;
    }
    __syncthreads();

    const float dwbr = dwb[c], bpr = bp[c];
    float dwr[25];
#pragma unroll
    for (int k = 0; k < 25; ++k) dwr[k] = dw[c*25+k];

    for (int g = 0; g < 4; ++g) {
        const int p0 = w*16 + g*4;          // 4 consecutive px in one row
        const int py = p0 >> 3, px0 = p0 & 7;
        float acc[4] = {dwbr, dwbr, dwbr, dwbr};
#pragma unroll
        for (int ky = 0; ky < 5; ++ky) {
            const int rbase = ((py+ky)*12 + px0)*64 + c;
#pragma unroll
            for (int kx8 = 0; kx8 < 8; ++kx8) {
                const float tv = __uint_as_float(
                    (unsigned)m2s[rbase + kx8*64] << 16);
#pragma unroll
                for (int j = 0; j < 4; ++j) {
                    const int kk = kx8 - j;
                    if (kk >= 0 && kk < 5)
                        acc[j] = fmaf(tv, dwr[ky*5 + kk], acc[j]);
                }
            }
        }
        size_t P[4];
#pragma unroll
        for (int j = 0; j < 4; ++j) {
            P[j] = (size_t)b*65536 + (size_t)(y0+py)*256 + (x0+px0+j);
            const float s = 1.f / (1.f + expf(-acc[j]));
            s_vm[w][j][c] = out[P[j]*64 + c] * (1.f + s);   // vm0 * (1+sig)
        }
        __builtin_amdgcn_wave_barrier();
        float oc[4] = {bpr, bpr, bpr, bpr};
        for (int c4 = 0; c4 < 16; ++c4) {
            float4 v4[4];
#pragma unroll
            for (int j = 0; j < 4; ++j)
                v4[j] = *(const float4*)&s_vm[w][j][c4*4];  // broadcast
            const float4 m4 = *(const float4*)&Mtl[c4*256 + lane*4];
#pragma unroll
            for (int u = 0; u < 4; ++u) {
#pragma unroll
                for (int j = 0; j < 4; ++j)
                    oc[j] = fmaf((&v4[j].x)[u], (&m4.x)[u], oc[j]);
            }
        }
#pragma unroll
        for (int j = 0; j < 4; ++j)
            out[P[j]*64 + c] = oc[j];
        __builtin_amdgcn_wave_barrier();
    }
}

// ---------------------------------------------------------------------------
// K5 (last): PE branch dwconv3x3 -> gelu -> dwconv3x3, += d_out.
// t1 stored bf16 in LDS (rounded). t1 outside image is ZERO.
// LDS = 36.8 + 12.8 = 49.6 KB -> 3 blocks/CU.
// ---------------------------------------------------------------------------
__global__ __launch_bounds__(256, 3) void k_pe(const float* __restrict__ x,
    const float* __restrict__ w1, const float* __restrict__ w2,
    float* __restrict__ out)
{
    __shared__ float xt[12*12*64];          // 36.8 KB
    __shared__ unsigned short t1[10*10*64]; // 12.8 KB bf16
    const int tid = threadIdx.x;
    const int bid = blockIdx.x;
    const int b = bid >> 10, tile = bid & 1023;
    const int y0 = (tile >> 5) * 8, x0 = (tile & 31) * 8;
    const int c = tid & 63;
    float w1r[9], w2r[9];
#pragma unroll
    for (int k = 0; k < 9; ++k) { w1r[k] = w1[c*9+k]; w2r[k] = w2[c*9+k]; }

    for (int i = tid; i < 12*12*64; i += 256) {
        int yy = i / 768, xx = (i % 768) >> 6;
        int gy = y0 + yy - 2, gx = x0 + xx - 2;
        float v = 0.f;
        if (gy >= 0 && gy < 256 && gx >= 0 && gx < 256)
            v = x[(((size_t)b*256 + gy)*256 + gx)*64 + c];
        xt[i] = v;
    }
    __syncthreads();
    for (int i = tid; i < 10*10*64; i += 256) {
        int yy = i / 640, xx = (i % 640) >> 6;
        int gy = y0 + yy - 1, gx = x0 + xx - 1;
        float val = 0.f;
        if (gy >= 0 && gy < 256 && gx >= 0 && gx < 256) {
            float acc = 0.f;
#pragma unroll
            for (int ky = 0; ky < 3; ++ky)
#pragma unroll
                for (int kx = 0; kx < 3; ++kx)
                    acc = fmaf(xt[((yy+ky)*12 + xx+kx)*64 + c], w1r[ky*3+kx], acc);
            val = 0.5f * acc * (1.f + erff(acc * 0.70710678118654752f));
        }
        unsigned u = __float_as_uint(val);
        u += 0x7FFFu + ((u >> 16) & 1u);    // RNE to bf16
        t1[i] = (unsigned short)(u >> 16);
    }
    __syncthreads();
    for (int i = tid; i < 8*8*64; i += 256) {
        int yy = i / 512, xx = (i % 512) >> 6;
        float acc = 0.f;
#pragma unroll
        for (int ky = 0; ky < 3; ++ky)
#pragma unroll
            for (int kx = 0; kx < 3; ++kx)
                acc = fmaf(__uint_as_float(
                          (unsigned)t1[((yy+ky)*10 + xx+kx)*64 + c] << 16),
                          w2r[ky*3+kx], acc);
        out[(((size_t)b*256 + y0+yy)*256 + x0+xx)*64 + c] += acc;
    }
}

extern "C" void kernel_launch(void* const* d_in, const int* in_sizes, int n_in,
                              void* d_out, int out_size, void* d_ws, size_t ws_size,
                              hipStream_t stream)
{
    const float* x    = (const float*)d_in[0];
    const float* mask = (const float*)d_in[1];
    const float* Wq   = (const float*)d_in[2];
    const float* Wk   = (const float*)d_in[3];
    const float* Wv   = (const float*)d_in[4];
    const float* resc = (const float*)d_in[5];
    const float* Wp   = (const float*)d_in[6];
    const float* bp   = (const float*)d_in[7];
    const float* mw1  = (const float*)d_in[8];
    const float* mb1  = (const float*)d_in[9];
    const float* mw2  = (const float*)d_in[10];
    const float* mb2  = (const float*)d_in[11];
    const float* mdw  = (const float*)d_in[12];
    const float* mdwb = (const float*)d_in[13];
    const float* pw1  = (const float*)d_in[14];
    const float* pw2  = (const float*)d_in[15];
    float* ws  = (float*)d_ws;
    __hip_bfloat16* m2 = (__hip_bfloat16*)((char*)d_ws + WS_M2_BYTE);
    float* out = (float*)d_out;

    hipMemsetAsync(ws, 0, (size_t)2304*sizeof(float), stream);   // G + ssq

    k_qkv3 <<<512,  256, 0, stream>>>(x, Wq, Wk, Wv, ws, out);   // v -> d_out
    k_attn <<<2,    256, 0, stream>>>(resc, Wp, ws);
    k_mask2<<<512,  256, 0, stream>>>(mask, mw1, mb1, mw2, mb2, out, m2);
    k_final<<<2048, 256, 0, stream>>>(m2, ws + WS_M, bp, mdw, mdwb, out);
    k_pe   <<<2048, 256, 0, stream>>>(x, pw1, pw2, out);
}

// Round 6
// 401.365 us; speedup vs baseline: 1.2267x; 1.2267x over previous
//
#include <hip/hip_runtime.h>
#include <hip/hip_bf16.h>
#include <math.h>

#define BB 2
#define NPIX 131072            // 2*256*256

// ws float header (4-slot accumulators to cut atomic contention 4x)
#define WS_G    0              // [slot4][B][1024]  (G[c=h*16+d][e])
#define WS_SSQ  8192           // [slot4][2][B][64] (0=q,1=k)
#define WS_M    9216           // [B][4096] folded Wp*blockdiag(attn), transposed
#define WS_HDR  17408
#define WS_M2_BYTE ((size_t)WS_HDR*4)   // m2 bf16: NPIX*64*2 = 16.78 MB

__device__ __forceinline__ unsigned short f2bf(float f) {
    unsigned u = __float_as_uint(f);
    u += 0x7FFFu + ((u >> 16) & 1u);            // RNE
    return (unsigned short)(u >> 16);
}
__device__ __forceinline__ float bf2f(unsigned short s) {
    return __uint_as_float((unsigned)s << 16);
}

// ---------------------------------------------------------------------------
// K1: q,k,v projections. v -> d_out. G + ssq atomics (4 slots) -> ws header.
// bf16 weights in blocked-f4 LDS (24 KB): LDS total 34.3 KB -> 4 blocks/CU.
// 1024 blocks x 128 px; per wave 32 px in 4 g-iters; x prefetched 1 g ahead.
// ---------------------------------------------------------------------------
__global__ __launch_bounds__(256, 4) void k_qkv3(const float* __restrict__ x,
    const float* __restrict__ Wq, const float* __restrict__ Wk,
    const float* __restrict__ Wv, float* __restrict__ ws,
    float* __restrict__ vout)
{
    __shared__ unsigned short wt[3*4096];   // 24 KB bf16, [mat][c4][o][u]
    __shared__ float buf[4][8][64];         // 8 KB per-wave
    __shared__ float s_ssq[4][2][64];       // 2 KB
    const int tid = threadIdx.x, lane = tid & 63, w = tid >> 6;
    const int blk = blockIdx.x, b = blk >> 9, slot = blk & 3;

    for (int i = tid; i < 4096; i += 256) {
        const int o = (i >> 2) & 63, gc = (i >> 8) * 4 + (i & 3);
        wt[i]        = f2bf(Wq[o*64 + gc]);
        wt[4096 + i] = f2bf(Wk[o*64 + gc]);
        wt[8192 + i] = f2bf(Wv[o*64 + gc]);
    }
    __syncthreads();

    float accG[16];
#pragma unroll
    for (int e = 0; e < 16; ++e) accG[e] = 0.f;
    float ssq_q = 0.f, ssq_k = 0.f;
    const int hbase = lane & 48;
    const int pix0 = blk*128 + w*32;

    float xr[8];
#pragma unroll
    for (int j = 0; j < 8; ++j)
        xr[j] = x[(size_t)(pix0+j)*64 + lane];

    for (int g = 0; g < 4; ++g) {
        const int pbase = pix0 + g*8;
#pragma unroll
        for (int j = 0; j < 8; ++j)
            buf[w][j][lane] = xr[j];
        __builtin_amdgcn_wave_barrier();
        if (g < 3) {                        // prefetch next g's x
#pragma unroll
            for (int j = 0; j < 8; ++j)
                xr[j] = x[(size_t)(pbase+8+j)*64 + lane];
        }

        float accQ[8], accK[8], accV[8];
#pragma unroll
        for (int j = 0; j < 8; ++j) { accQ[j]=0.f; accK[j]=0.f; accV[j]=0.f; }
        for (int c4 = 0; c4 < 16; ++c4) {
            float4 x4[8];
#pragma unroll
            for (int j = 0; j < 8; ++j)
                x4[j] = *(const float4*)&buf[w][j][c4*4];       // broadcast
            const ushort4 q4 = *(const ushort4*)&wt[c4*256 + lane*4];
            const ushort4 k4 = *(const ushort4*)&wt[4096 + c4*256 + lane*4];
            const ushort4 v4 = *(const ushort4*)&wt[8192 + c4*256 + lane*4];
            const float wqf[4] = {bf2f(q4.x), bf2f(q4.y), bf2f(q4.z), bf2f(q4.w)};
            const float wkf[4] = {bf2f(k4.x), bf2f(k4.y), bf2f(k4.z), bf2f(k4.w)};
            const float wvf[4] = {bf2f(v4.x), bf2f(v4.y), bf2f(v4.z), bf2f(v4.w)};
#pragma unroll
            for (int u = 0; u < 4; ++u) {
#pragma unroll
                for (int j = 0; j < 8; ++j) {
                    const float xc = (&x4[j].x)[u];
                    accQ[j] = fmaf(xc, wqf[u], accQ[j]);
                    accK[j] = fmaf(xc, wkf[u], accK[j]);
                    accV[j] = fmaf(xc, wvf[u], accV[j]);
                }
            }
        }
        __builtin_amdgcn_wave_barrier();
#pragma unroll
        for (int j = 0; j < 8; ++j) {
            vout[(size_t)(pbase+j)*64 + lane] = accV[j];
            buf[w][j][lane] = accQ[j];                          // x dead
            ssq_q = fmaf(accQ[j], accQ[j], ssq_q);
            ssq_k = fmaf(accK[j], accK[j], ssq_k);
        }
        __builtin_amdgcn_wave_barrier();
        // Gram: lane c=h*16+d holds k; q[h*16+e] broadcast
#pragma unroll
        for (int j = 0; j < 8; ++j) {
            const float kv = accK[j];
#pragma unroll
            for (int e4 = 0; e4 < 4; ++e4) {
                float4 q4 = *(const float4*)&buf[w][j][hbase + e4*4];
                accG[e4*4+0] = fmaf(kv, q4.x, accG[e4*4+0]);
                accG[e4*4+1] = fmaf(kv, q4.y, accG[e4*4+1]);
                accG[e4*4+2] = fmaf(kv, q4.z, accG[e4*4+2]);
                accG[e4*4+3] = fmaf(kv, q4.w, accG[e4*4+3]);
            }
        }
        __builtin_amdgcn_wave_barrier();
    }

    __syncthreads();    // waves below write across other waves' buf regions

    // two-phase block reduction of G in buf (2048 floats), layout [w2][e][lane]
    float* gr = &buf[0][0][0];
    if (w < 2) {
#pragma unroll
        for (int e = 0; e < 16; ++e) gr[w*1024 + e*64 + lane] = accG[e];
    }
    s_ssq[w][0][lane] = ssq_q;
    s_ssq[w][1][lane] = ssq_k;
    __syncthreads();
    if (w >= 2) {
#pragma unroll
        for (int e = 0; e < 16; ++e) gr[(w-2)*1024 + e*64 + lane] += accG[e];
    }
    __syncthreads();
    float* Gg = ws + WS_G + (size_t)slot*2048 + (size_t)b*1024;
    for (int idx = tid; idx < 1024; idx += 256) {
        const int e = idx >> 6, c = idx & 63;
        atomicAdd(&Gg[c*16 + e], gr[idx] + gr[1024 + idx]);
    }
    if (tid < 128) {
        const int which = tid >> 6, cidx = tid & 63;
        float s = s_ssq[0][which][cidx] + s_ssq[1][which][cidx]
                + s_ssq[2][which][cidx] + s_ssq[3][which][cidx];
        atomicAdd(ws + WS_SSQ + (size_t)slot*256 + which*128 + b*64 + cidx, s);
    }
}

// ---------------------------------------------------------------------------
// K2: m1 = mask@w1^T+b1 ; vm0 = v*m1 -> d_out (in place) ; m2 -> ws bf16.
// bf16 weights (16 KB): LDS 24.3 KB. 1024 blocks x 128 px, prefetch 1 g ahead.
// ---------------------------------------------------------------------------
__global__ __launch_bounds__(256, 4) void k_mask2(const float* __restrict__ mask,
    const float* __restrict__ w1, const float* __restrict__ b1,
    const float* __restrict__ w2, const float* __restrict__ b2,
    float* __restrict__ vio, __hip_bfloat16* __restrict__ m2out)
{
    __shared__ unsigned short wt[2*4096];   // 16 KB bf16 blocked-f4
    __shared__ float buf[4][8][64];         // 8 KB
    const int tid = threadIdx.x, lane = tid & 63, w = tid >> 6;
    const int blk = blockIdx.x;

    for (int i = tid; i < 4096; i += 256) {
        const int o = (i >> 2) & 63, gc = (i >> 8) * 4 + (i & 3);
        wt[i]        = f2bf(w1[o*64 + gc]);
        wt[4096 + i] = f2bf(w2[o*64 + gc]);
    }
    __syncthreads();
    const float bb1 = b1[lane], bb2 = b2[lane];
    const int pix0 = blk*128 + w*32;

    float mreg[8], vreg[8];
#pragma unroll
    for (int j = 0; j < 8; ++j) {
        mreg[j] = mask[(size_t)(pix0+j)*64 + lane];
        vreg[j] = vio[(size_t)(pix0+j)*64 + lane];
    }

    for (int g = 0; g < 4; ++g) {
        const int pbase = pix0 + g*8;
#pragma unroll
        for (int j = 0; j < 8; ++j)
            buf[w][j][lane] = mreg[j];
        __builtin_amdgcn_wave_barrier();
        if (g < 3) {
#pragma unroll
            for (int j = 0; j < 8; ++j)
                mreg[j] = mask[(size_t)(pbase+8+j)*64 + lane];
        }

        float acc1[8];
#pragma unroll
        for (int j = 0; j < 8; ++j) acc1[j] = bb1;
        for (int c4 = 0; c4 < 16; ++c4) {
            float4 x4[8];
#pragma unroll
            for (int j = 0; j < 8; ++j)
                x4[j] = *(const float4*)&buf[w][j][c4*4];
            const ushort4 u4 = *(const ushort4*)&wt[c4*256 + lane*4];
            const float wf[4] = {bf2f(u4.x), bf2f(u4.y), bf2f(u4.z), bf2f(u4.w)};
#pragma unroll
            for (int u = 0; u < 4; ++u)
#pragma unroll
                for (int j = 0; j < 8; ++j)
                    acc1[j] = fmaf((&x4[j].x)[u], wf[u], acc1[j]);
        }
        __builtin_amdgcn_wave_barrier();
#pragma unroll
        for (int j = 0; j < 8; ++j) {
            vio[(size_t)(pbase+j)*64 + lane] = vreg[j] * acc1[j];   // vm0
            buf[w][j][lane] = acc1[j];                              // mask dead
        }
        __builtin_amdgcn_wave_barrier();
        if (g < 3) {
#pragma unroll
            for (int j = 0; j < 8; ++j)
                vreg[j] = vio[(size_t)(pbase+8+j)*64 + lane];       // next g's v
        }

        float acc2[8];
#pragma unroll
        for (int j = 0; j < 8; ++j) acc2[j] = bb2;
        for (int c4 = 0; c4 < 16; ++c4) {
            float4 a4[8];
#pragma unroll
            for (int j = 0; j < 8; ++j)
                a4[j] = *(const float4*)&buf[w][j][c4*4];
            const ushort4 u4 = *(const ushort4*)&wt[4096 + c4*256 + lane*4];
            const float wf[4] = {bf2f(u4.x), bf2f(u4.y), bf2f(u4.z), bf2f(u4.w)};
#pragma unroll
            for (int u = 0; u < 4; ++u)
#pragma unroll
                for (int j = 0; j < 8; ++j)
                    acc2[j] = fmaf((&a4[j].x)[u], wf[u], acc2[j]);
        }
#pragma unroll
        for (int j = 0; j < 8; ++j)
            m2out[(size_t)(pbase+j)*64 + lane] = __float2bfloat16(acc2[j]);
        __builtin_amdgcn_wave_barrier();
    }
}

// ---------------------------------------------------------------------------
// K3: softmax over normalized Gram (sum 4 slots), folded with Wp:
//   Mt[b][c=h*16+e][o] = sum_d Wp[o][h*16+d] * attn[b][h][d][e].  2 blocks.
// ---------------------------------------------------------------------------
__global__ __launch_bounds__(256) void k_attn(const float* __restrict__ rescale,
    const float* __restrict__ Wp, float* __restrict__ ws)
{
    __shared__ float sAtt[1024];        // [h][d][e]
    const int b = blockIdx.x, t = threadIdx.x;
    const int d = t >> 4, e = t & 15;
#pragma unroll
    for (int h = 0; h < 4; ++h) {
        float g = 0.f, nk2 = 0.f, nq2 = 0.f;
#pragma unroll
        for (int s = 0; s < 4; ++s) {
            g   += ws[WS_G + s*2048 + b*1024 + (h*16+d)*16 + e];
            nk2 += ws[WS_SSQ + s*256 + 128 + b*64 + h*16 + d];
            nq2 += ws[WS_SSQ + s*256 +   0 + b*64 + h*16 + e];
        }
        float nk = fmaxf(sqrtf(nk2), 1e-12f);
        float nq = fmaxf(sqrtf(nq2), 1e-12f);
        float val = g / (nk*nq) * rescale[h];
        float m = val;
        for (int off = 1; off < 16; off <<= 1) m = fmaxf(m, __shfl_xor(m, off, 16));
        float ev = expf(val - m);
        float s2 = ev;
        for (int off = 1; off < 16; off <<= 1) s2 += __shfl_xor(s2, off, 16);
        sAtt[h*256 + d*16 + e] = ev / s2;
    }
    __syncthreads();
    float* Mtb = ws + WS_M + (size_t)b*4096;
    for (int idx = t; idx < 4096; idx += 256) {
        const int c = idx >> 6, o = idx & 63, h = c >> 4, ee = c & 15;
        float acc = 0.f;
#pragma unroll
        for (int d2 = 0; d2 < 16; ++d2)
            acc = fmaf(Wp[o*64 + h*16 + d2], sAtt[h*256 + d2*16 + ee], acc);
        Mtb[c*64 + o] = acc;
    }
}

// ---------------------------------------------------------------------------
// K4: per 8x8 tile: dwconv5x5(m2 bf16 halo)+dwb -> sigmoid ->
//   vm = vm0(d_out)*(1+sig) -> out = Mt . vm + bp.
// LDS = 18.4(m2s) + 8(Mtl bf16) + 4(s_vm) = 30.5 KB -> 4+ blocks/CU.
// ---------------------------------------------------------------------------
__global__ __launch_bounds__(256, 4) void k_final(
    const __hip_bfloat16* __restrict__ m2g, const float* __restrict__ wsM,
    const float* __restrict__ bp, const float* __restrict__ dw,
    const float* __restrict__ dwb, float* __restrict__ out)
{
    __shared__ unsigned short m2s[144*64];  // 18.4 KB bf16 halo (0 outside)
    __shared__ unsigned short Mtl[4096];    // 8 KB bf16 blocked-f4 [c4][o][u]
    __shared__ float s_vm[4][4][64];        // per-wave
    const int tid = threadIdx.x, lane = tid & 63, w = tid >> 6;
    const int bid = blockIdx.x;
    const int b = bid >> 10, tile = bid & 1023;
    const int y0 = (tile >> 5) * 8, x0 = (tile & 31) * 8;
    const int c = lane;

    const float* Msrc = wsM + (size_t)b*4096;
    for (int i = tid; i < 4096; i += 256) {
        const int o = (i >> 2) & 63, gc = (i >> 8) * 4 + (i & 3);
        Mtl[i] = f2bf(Msrc[gc*64 + o]);
    }
    for (int i2 = tid; i2 < 2304; i2 += 256) {
        const int pos = i2 >> 4, c4 = (i2 & 15) * 4;
        const int yy = pos / 12, xx = pos - yy*12;
        const int gy = y0 + yy - 2, gx = x0 + xx - 2;
        ushort4 us = make_ushort4(0, 0, 0, 0);
        if (gy >= 0 && gy < 256 && gx >= 0 && gx < 256)
            us = *(const ushort4*)&m2g[(((size_t)b*256 + gy)*256 + gx)*64 + c4];
        *(ushort4*)&m2s[pos*64 + c4] = us;
    }
    __syncthreads();

    const float dwbr = dwb[c], bpr = bp[c];
    float dwr[25];
#pragma unroll
    for (int k = 0; k < 25; ++k) dwr[k] = dw[c*25+k];

    for (int g = 0; g < 4; ++g) {
        const int p0 = w*16 + g*4;          // 4 consecutive px in one row
        const int py = p0 >> 3, px0 = p0 & 7;
        float acc[4] = {dwbr, dwbr, dwbr, dwbr};
#pragma unroll
        for (int ky = 0; ky < 5; ++ky) {
            const int rbase = ((py+ky)*12 + px0)*64 + c;
#pragma unroll
            for (int kx8 = 0; kx8 < 8; ++kx8) {
                const float tv = bf2f(m2s[rbase + kx8*64]);
#pragma unroll
                for (int j = 0; j < 4; ++j) {
                    const int kk = kx8 - j;
                    if (kk >= 0 && kk < 5)
                        acc[j] = fmaf(tv, dwr[ky*5 + kk], acc[j]);
                }
            }
        }
        size_t P[4];
#pragma unroll
        for (int j = 0; j < 4; ++j) {
            P[j] = (size_t)b*65536 + (size_t)(y0+py)*256 + (x0+px0+j);
            const float s = 1.f / (1.f + expf(-acc[j]));
            s_vm[w][j][c] = out[P[j]*64 + c] * (1.f + s);   // vm0 * (1+sig)
        }
        __builtin_amdgcn_wave_barrier();
        float oc[4] = {bpr, bpr, bpr, bpr};
        for (int c4 = 0; c4 < 16; ++c4) {
            float4 v4[4];
#pragma unroll
            for (int j = 0; j < 4; ++j)
                v4[j] = *(const float4*)&s_vm[w][j][c4*4];  // broadcast
            const ushort4 m4 = *(const ushort4*)&Mtl[c4*256 + lane*4];
            const float mf[4] = {bf2f(m4.x), bf2f(m4.y), bf2f(m4.z), bf2f(m4.w)};
#pragma unroll
            for (int u = 0; u < 4; ++u)
#pragma unroll
                for (int j = 0; j < 4; ++j)
                    oc[j] = fmaf((&v4[j].x)[u], mf[u], oc[j]);
        }
#pragma unroll
        for (int j = 0; j < 4; ++j)
            out[P[j]*64 + c] = oc[j];
        __builtin_amdgcn_wave_barrier();
    }
}

// ---------------------------------------------------------------------------
// K5 (last): PE branch dwconv3x3 -> gelu -> dwconv3x3, += d_out.
// xt and t1 both bf16 in LDS: 18.4 + 12.8 = 31.2 KB -> 5 blocks/CU.
// t1 outside image is ZERO (conv2 padding semantics).
// ---------------------------------------------------------------------------
__global__ __launch_bounds__(256, 5) void k_pe(const float* __restrict__ x,
    const float* __restrict__ w1, const float* __restrict__ w2,
    float* __restrict__ out)
{
    __shared__ unsigned short xt[12*12*64];     // 18.4 KB bf16
    __shared__ unsigned short t1[10*10*64];     // 12.8 KB bf16
    const int tid = threadIdx.x;
    const int bid = blockIdx.x;
    const int b = bid >> 10, tile = bid & 1023;
    const int y0 = (tile >> 5) * 8, x0 = (tile & 31) * 8;
    const int c = tid & 63;
    float w1r[9], w2r[9];
#pragma unroll
    for (int k = 0; k < 9; ++k) { w1r[k] = w1[c*9+k]; w2r[k] = w2[c*9+k]; }

    for (int i = tid; i < 12*12*64; i += 256) {
        int yy = i / 768, xx = (i % 768) >> 6;
        int gy = y0 + yy - 2, gx = x0 + xx - 2;
        float v = 0.f;
        if (gy >= 0 && gy < 256 && gx >= 0 && gx < 256)
            v = x[(((size_t)b*256 + gy)*256 + gx)*64 + c];
        xt[i] = f2bf(v);
    }
    __syncthreads();
    for (int i = tid; i < 10*10*64; i += 256) {
        int yy = i / 640, xx = (i % 640) >> 6;
        int gy = y0 + yy - 1, gx = x0 + xx - 1;
        float val = 0.f;
        if (gy >= 0 && gy < 256 && gx >= 0 && gx < 256) {
            float acc = 0.f;
#pragma unroll
            for (int ky = 0; ky < 3; ++ky)
#pragma unroll
                for (int kx = 0; kx < 3; ++kx)
                    acc = fmaf(bf2f(xt[((yy+ky)*12 + xx+kx)*64 + c]),
                               w1r[ky*3+kx], acc);
            val = 0.5f * acc * (1.f + erff(acc * 0.70710678118654752f));
        }
        t1[i] = f2bf(val);
    }
    __syncthreads();
    for (int i = tid; i < 8*8*64; i += 256) {
        int yy = i / 512, xx = (i % 512) >> 6;
        float acc = 0.f;
#pragma unroll
        for (int ky = 0; ky < 3; ++ky)
#pragma unroll
            for (int kx = 0; kx < 3; ++kx)
                acc = fmaf(bf2f(t1[((yy+ky)*10 + xx+kx)*64 + c]),
                           w2r[ky*3+kx], acc);
        out[(((size_t)b*256 + y0+yy)*256 + x0+xx)*64 + c] += acc;
    }
}

extern "C" void kernel_launch(void* const* d_in, const int* in_sizes, int n_in,
                              void* d_out, int out_size, void* d_ws, size_t ws_size,
                              hipStream_t stream)
{
    const float* x    = (const float*)d_in[0];
    const float* mask = (const float*)d_in[1];
    const float* Wq   = (const float*)d_in[2];
    const float* Wk   = (const float*)d_in[3];
    const float* Wv   = (const float*)d_in[4];
    const float* resc = (const float*)d_in[5];
    const float* Wp   = (const float*)d_in[6];
    const float* bp   = (const float*)d_in[7];
    const float* mw1  = (const float*)d_in[8];
    const float* mb1  = (const float*)d_in[9];
    const float* mw2  = (const float*)d_in[10];
    const float* mb2  = (const float*)d_in[11];
    const float* mdw  = (const float*)d_in[12];
    const float* mdwb = (const float*)d_in[13];
    const float* pw1  = (const float*)d_in[14];
    const float* pw2  = (const float*)d_in[15];
    float* ws  = (float*)d_ws;
    __hip_bfloat16* m2 = (__hip_bfloat16*)((char*)d_ws + WS_M2_BYTE);
    float* out = (float*)d_out;

    hipMemsetAsync(ws, 0, (size_t)9216*sizeof(float), stream);   // G + ssq slots

    k_qkv3 <<<1024, 256, 0, stream>>>(x, Wq, Wk, Wv, ws, out);   // v -> d_out
    k_attn <<<2,    256, 0, stream>>>(resc, Wp, ws);
    k_mask2<<<1024, 256, 0, stream>>>(mask, mw1, mb1, mw2, mb2, out, m2);
    k_final<<<2048, 256, 0, stream>>>(m2, ws + WS_M, bp, mdw, mdwb, out);
    k_pe   <<<2048, 256, 0, stream>>>(x, pw1, pw2, out);
}